// Round 12
// baseline (3734.655 us; speedup 1.0000x reference)
//
#include <hip/hip_runtime.h>
#include <cstdint>
#include <cstddef>

#define NEGV -1.0e9f
#define NB 4              // row-blocks per batch
#define BW 4              // waves per row-block

// Branchless logaddexp, bit-identical to the verified branch form.
__device__ __forceinline__ float lse_f(float a, float b) {
    float d = a - b;
    float m = fmaxf(a, b);
    return m + log1pf(expf(-fabsf(d)));
}

// Packed anti-diagonal geometry for the bundle buffer.
__device__ __forceinline__ void diag_geo(int d, int& st, int& L, int& tlo) {
    if (d < 64)        { st = (d * (d + 1)) >> 1;       L = d + 1;      tlo = 0; }
    else if (d < 1024) { st = 2080 + ((d - 64) << 6);   L = 64;         tlo = 0; }
    else               { int u = d - 1024;
                         st = 63520 + (u << 6) - ((u * (u + 1)) >> 1);
                         L = 63 - u;                    tlo = u + 1; }
}

// ---------------------------------------------------------------------------
// K1: T = emb @ W + b   (f64 accumulate), T: [22][512]
// ---------------------------------------------------------------------------
__global__ void k_embed(const float* __restrict__ emb, const float* __restrict__ W,
                        const float* __restrict__ b, double* __restrict__ T) {
    int idx = blockIdx.x * blockDim.x + threadIdx.x;
    if (idx >= 22 * 512) return;
    int a = idx >> 9, d = idx & 511;
    double acc = (double)b[d];
    const float* er = emb + a * 512;
    for (int k = 0; k < 512; ++k) acc += (double)er[k] * (double)W[k * 512 + d];
    T[idx] = acc;
}

// ---------------------------------------------------------------------------
// K2: G = T @ T^T (22x22), u1/u2 = T @ Wg halves, A[b] via index sums
// ---------------------------------------------------------------------------
__global__ void k_gau(const double* __restrict__ T, const int* __restrict__ x,
                      const int* __restrict__ y, const float* __restrict__ Wg,
                      const float* __restrict__ bg,
                      double* __restrict__ G, double* __restrict__ Aout) {
    __shared__ double u1s[22], u2s[22];
    int t = threadIdx.x;
    if (t < 484) {
        int a = t / 22, c = t % 22;
        const double* ra = T + a * 512;
        const double* rc = T + c * 512;
        double acc = 0.0;
        for (int d = 0; d < 512; ++d) acc += ra[d] * rc[d];
        G[t] = acc;
    }
    if (t < 22) {
        double acc = 0.0;
        const double* ra = T + t * 512;
        for (int d = 0; d < 512; ++d) acc += ra[d] * (double)Wg[d];
        u1s[t] = acc;
    } else if (t >= 64 && t < 86) {
        int a = t - 64;
        double acc = 0.0;
        const double* ra = T + a * 512;
        for (int d = 0; d < 512; ++d) acc += ra[d] * (double)Wg[512 + d];
        u2s[a] = acc;
    }
    __syncthreads();
    int w = t >> 6, lane = t & 63;
    const int* xb = x + w * 1024;
    const int* yb = y + w * 1024;
    double s = 0.0;
    for (int i = lane; i < 1024; i += 64) s += u1s[xb[i]] + u2s[yb[i]];
    for (int off = 32; off > 0; off >>= 1) s += __shfl_down(s, off);
    if (lane == 0) Aout[w] = s * (1.0 / 1024.0) + (double)bg[0];
}

// ---------------------------------------------------------------------------
// K3a: init V boundary (row 0 / col 0) + zero inter-block flags.
// ---------------------------------------------------------------------------
__global__ void k_vinit(float* __restrict__ Vbuf, int* __restrict__ gflag) {
    int b = blockIdx.x, t = threadIdx.x;
    float* Vb = Vbuf + (size_t)b * (1025 * 1025);
    Vb[t] = (t == 0) ? 0.0f : NEGV;                 // V[0][t]
    if (t == 0) Vb[1024] = NEGV;                    // V[0][1024]
    Vb[(size_t)(t + 1) * 1025] = NEGV;              // V[t+1][0]
    if (b == 0 && t < 64) gflag[t] = 0;
}

// ---------------------------------------------------------------------------
// K3b: software-pipelined split forward. Lanes offset by 2 columns; each step
//      computes outer(col jo) [using inner_c from last step] AND inner(col
//      jo+1) [from lane t-1's register history via 2 shfls] — the two lse
//      chains are independent -> per-step serial chain ~= ONE lse, not two.
//      Lane-0 sources (topbuf / producer row in global) prefetched one step
//      ahead. Per-cell op sequence verbatim -> bit-identical V.
// ---------------------------------------------------------------------------
__global__ __launch_bounds__(256) void k_fwds(const int* __restrict__ x,
                                              const int* __restrict__ y,
                                              const double* __restrict__ G,
                                              const double* __restrict__ Aarr,
                                              float* __restrict__ Vbuf,
                                              int* __restrict__ gflag) {
    __shared__ float Gs[484];
    __shared__ int ys_s[1024];
    __shared__ float topbuf[BW][1024];   // topbuf[w][c] = V[256p + 64w][c+1]
    __shared__ int prog[BW];

    const int bid = blockIdx.x;
    const int b = bid & 7;               // batch (XCD-affine: same batch -> same XCD)
    const int p = bid >> 3;              // row-block 0..NB-1
    const int tid = threadIdx.x;         // 0..255
    const int w = tid >> 6;              // wave within block
    const int t = tid & 63;              // lane
    const int grow = (p << 8) + tid;     // global (row-1)
    float* Vb = Vbuf + (size_t)b * (1025 * 1025);

    for (int q = tid; q < 484; q += 256) Gs[q] = (float)G[q];
    for (int q = tid; q < 1024; q += 256) ys_s[q] = y[(b << 10) + q];
    if (tid < BW) prog[tid] = 0;
    const int xs = x[(b << 10) + grow];
    __syncthreads();

    const float A = (float)Aarr[b];
    const float* Grow = Gs + xs * 22;
    float* vst = Vb + (size_t)(grow + 1) * 1025 + 1;      // vst[j-1] = V[row][j]
    const float* tsrc = Vb + (size_t)(p << 8) * 1025;     // V[256p][*]

    // lane-0 source state (one-step-ahead prefetch)
    float cur_vu = NEGV, prev_vu = NEGV;
    if (t == 0) {
        if (w == 0) {
            if (p == 0) { cur_vu = NEGV; prev_vu = 0.0f; }          // row 0: V[0][1]=NEGV, V[0][0]=0
            else {
                while (__hip_atomic_load(&gflag[(b << 2) + p - 1], __ATOMIC_ACQUIRE,
                                         __HIP_MEMORY_SCOPE_AGENT) < 64)
                    __builtin_amdgcn_s_sleep(2);
                prev_vu = tsrc[0];                                  // NEGV boundary
                cur_vu  = tsrc[1];
            }
        } else {
            while (__hip_atomic_load(&prog[w], __ATOMIC_ACQUIRE,
                                     __HIP_MEMORY_SCOPE_WORKGROUP) < 16)
                __builtin_amdgcn_s_sleep(1);
            prev_vu = NEGV;                                         // V[.][0]
            cur_vu  = topbuf[w][0];                                 // V[row-1][1]
        }
    }

    float vp = NEGV, vp2 = NEGV, inner_c = 0.f;

    for (int s = -1; s <= 1533; ++s) {
        const int jo = s - 2 * tid + 1;      // outer column this step
        const int ji = jo + 1;               // inner column this step
        const float sh_vu = __shfl_up(vp, 1);    // lane t-1: v(r-1, ji)
        const float sh_vd = __shfl_up(vp2, 1);   // lane t-1: v(r-1, ji-1)

        float inner_n = 0.f;
        const bool ji_act = (ji >= 1) && (ji <= 1024);
        if (ji_act) {
            float vu_i, vdg_i;
            if (t == 0) {
                vu_i = cur_vu; vdg_i = prev_vu;
                // prefetch source for column ji+1
                if (ji < 1024) {
                    float nxt;
                    if (w == 0) {
                        if (p == 0) nxt = NEGV;
                        else {
                            if ((ji & 63) == 0) {
                                int tgt = ji + 64; if (tgt > 1024) tgt = 1024;
                                while (__hip_atomic_load(&gflag[(b << 2) + p - 1],
                                        __ATOMIC_ACQUIRE, __HIP_MEMORY_SCOPE_AGENT) < tgt)
                                    __builtin_amdgcn_s_sleep(2);
                            }
                            nxt = tsrc[ji + 1];
                        }
                    } else {
                        if ((ji & 15) == 0) {
                            int tgt = ji + 16; if (tgt > 1024) tgt = 1024;
                            while (__hip_atomic_load(&prog[w], __ATOMIC_ACQUIRE,
                                    __HIP_MEMORY_SCOPE_WORKGROUP) < tgt)
                                __builtin_amdgcn_s_sleep(1);
                        }
                        nxt = topbuf[w][ji];           // V[row-1][ji+1]
                    }
                    prev_vu = cur_vu; cur_vu = nxt;
                }
            } else {
                vu_i = sh_vu; vdg_i = sh_vd;
            }
            inner_n = lse_f(vu_i + A, vdg_i);        // independent of outer below
        }

        if (jo >= 1 && jo <= 1024) {
            float outer = lse_f(inner_c, vp + A);
            float v = Grow[ys_s[jo - 1]] + outer;
            vst[jo - 1] = v;                          // global store stays in flight
            if (t == 63) {
                if (w < BW - 1) {
                    topbuf[w + 1][jo - 1] = v;
                    if ((jo & 15) == 0)
                        __hip_atomic_store(&prog[w + 1], jo, __ATOMIC_RELEASE,
                                           __HIP_MEMORY_SCOPE_WORKGROUP);
                } else if (p < NB - 1) {
                    if ((jo & 63) == 0) {
                        __threadfence();
                        __hip_atomic_store(&gflag[(b << 2) + p], jo,
                                           __ATOMIC_RELEASE, __HIP_MEMORY_SCOPE_AGENT);
                    }
                }
            }
            vp2 = vp; vp = v;
        }
        inner_c = inner_n;
    }
}

// ---------------------------------------------------------------------------
// K4: weight kernel — recompute each cell's softmax weights (bit-identical
//     inputs from stored V), scatter into the packed-diagonal bundle layout.
// ---------------------------------------------------------------------------
__global__ __launch_bounds__(256) void k_wb(const double* __restrict__ Aarr,
                                            const float* __restrict__ Vbuf,
                                            float* __restrict__ bw) {
    int idx = blockIdx.x * 256 + threadIdx.x;
    int b = idx >> 20;
    int cell = idx & 1048575;
    int i = (cell >> 10) + 1;        // 1..1024
    int j = (cell & 1023) + 1;       // 1..1024
    const float* Vb = Vbuf + (size_t)b * (1025 * 1025);
    float vu  = Vb[(size_t)(i - 1) * 1025 + j];
    float vdg = Vb[(size_t)(i - 1) * 1025 + (j - 1)];
    float vl  = Vb[(size_t)i * 1025 + (j - 1)];
    float A = (float)Aarr[b];
    float t1 = vu + A;
    float t2 = vl + A;
    float di = t1 - vdg;
    float inner = (di > 0.f) ? (t1  + log1pf(expf(-di)))
                             : (vdg + log1pf(expf(di)));
    float dw = inner - t2;
    float outer = (dw > 0.f) ? (inner + log1pf(expf(-dw)))
                             : (t2    + log1pf(expf(dw)));
    float go1 = expf(inner - outer);
    float wlW = expf(t2 - outer);
    float wuW = go1 * expf(t1 - inner);
    float wdW = go1 * expf(vdg - inner);
    float* bbp = bw + (size_t)b * 3145728;

    if (i >= 2) {        // wu -> consumer (i-1, j)
        int rb = (i - 2) >> 4, q = (i - 2) & 15, cj = j - 1;
        int st, L, tlo; diag_geo(rb + cj, st, L, tlo);
        int f = 3 * q;
        bbp[(size_t)st * 48 + (size_t)(f >> 2) * 4 * L + ((rb - tlo) << 2) + (f & 3)] = wuW;
    }
    if (i >= 2 && j >= 2) {   // wd -> consumer (i-1, j-1)
        int rb = (i - 2) >> 4, q = (i - 2) & 15, cj = j - 2;
        int st, L, tlo; diag_geo(rb + cj, st, L, tlo);
        int f = 3 * q + 1;
        bbp[(size_t)st * 48 + (size_t)(f >> 2) * 4 * L + ((rb - tlo) << 2) + (f & 3)] = wdW;
    }
    if (j >= 2) {        // wl -> consumer (i, j-1)
        int rb = (i - 1) >> 4, q = (i - 1) & 15, cj = j - 2;
        int st, L, tlo; diag_geo(rb + cj, st, L, tlo);
        int f = 3 * q + 2;
        bbp[(size_t)st * 48 + (size_t)(f >> 2) * 4 * L + ((rb - tlo) << 2) + (f & 3)] = wlW;
    }
}

// ---------------------------------------------------------------------------
// K5: single-launch backward, packed-diagonal coalesced bundle reads.
//     (verbatim from the verified round-9 kernel; bit-identical E order)
// ---------------------------------------------------------------------------
__global__ __launch_bounds__(64) void k_bwd16(const float* __restrict__ bw,
                                              float* __restrict__ out) {
    const int t = threadIdx.x;
    const int b = blockIdx.x;
    const float* bb = bw + (size_t)b * 3145728;
    float* ob = out + ((size_t)b << 20);
    const int r0 = t << 4;              // (i-1) base = 16t

    float e[16];
    float4 cwv[12], pfv[12];
    #pragma unroll
    for (int q = 0; q < 16; ++q) e[q] = 0.f;

    {
        int st, L, tlo; diag_geo(t + 1023, st, L, tlo);
        const float* base = bb + (size_t)st * 48;
        #pragma unroll
        for (int k = 0; k < 12; ++k)
            cwv[k] = *(const float4*)(base + (size_t)k * 4 * L);
    }

    float sdb = 0.f;
    for (int s = 0; s < 1087; ++s) {
        float dn = __shfl_down(e[0], 1);    // lane t+1's top value at col cj
        const int d = 1086 - s;
        const int cj = d - t;               // this lane's column (j-1)
        if (cj >= 0 && cj < 1024) {
            {
                int st, L, tlo; diag_geo(d - 1, st, L, tlo);
                const int p = t - tlo;
                const float* base = bb + (size_t)st * 48 + ((size_t)p << 2);
                #pragma unroll
                for (int k = 0; k < 12; ++k)
                    pfv[k] = *(const float4*)(base + (size_t)k * 4 * L);
            }
            const float* F = (const float*)cwv;

            float old_b = e[15];
            float eu = (t == 63) ? 0.f : dn;
            float ed = (t == 63) ? 0.f : sdb;
            float v = eu * F[45] + ed * F[46] + old_b * F[47];
            if (t == 63 && cj == 1023) v = 1.0f;    // seed E[1024][1024] = 1
            e[15] = v;
            float new_b = v;
            #pragma unroll
            for (int q = 14; q >= 0; --q) {
                float oq = e[q];
                v = new_b * F[3 * q] + old_b * F[3 * q + 1] + oq * F[3 * q + 2];
                e[q] = v;
                new_b = v; old_b = oq;
            }
            #pragma unroll
            for (int k = 0; k < 4; ++k)
                *(float4*)&ob[(size_t)cj * 1024 + r0 + 4 * k] =
                    make_float4(e[4*k], e[4*k+1], e[4*k+2], e[4*k+3]);
            #pragma unroll
            for (int k = 0; k < 12; ++k) cwv[k] = pfv[k];
        }
        sdb = dn;
    }
}

// ---------------------------------------------------------------------------
// Fallback: round-2 monolithic forward+backward (used only if ws too small).
// ---------------------------------------------------------------------------
template <bool FAITHFUL>
__global__ __launch_bounds__(1024) void k_dp(const int* __restrict__ x,
                                             const int* __restrict__ y,
                                             const double* __restrict__ G,
                                             const double* __restrict__ Aarr,
                                             float2* __restrict__ wbuf,
                                             float* __restrict__ wdbuf,
                                             float* __restrict__ out) {
    __shared__ float Gs[484];
    __shared__ int xs[1024], ys[1024];
    __shared__ float D[3][1025];
    __shared__ float E[3][1026];

    const int b = blockIdx.x;
    const int t = threadIdx.x;
    const int i = t + 1;

    if (t < 484) Gs[t] = (float)G[t];
    xs[t] = x[(b << 10) + t];
    ys[t] = y[(b << 10) + t];
    D[0][t + 1] = NEGV;
    D[1][t + 1] = NEGV;
    E[0][t] = 0.f; E[1][t] = 0.f; E[2][t] = 0.f;
    if (t == 0) {
        D[0][0] = 0.0f;
        D[1][0] = NEGV;
        E[0][1024] = 0.f; E[0][1025] = 0.f;
        E[1][1024] = 0.f; E[1][1025] = 0.f;
        E[2][1024] = 0.f; E[2][1025] = 0.f;
    }
    __syncthreads();

    const float A = (float)Aarr[b];
    const float* Grow = Gs + xs[t] * 22;
    float2* wb = wbuf + ((size_t)b << 20);
    float*  wdb = wdbuf + ((size_t)b << 20);

    for (int k = 2; k <= 2048; ++k) {
        const int cur = k % 3, p1 = (k + 2) % 3, p2 = (k + 1) % 3;
        const int j = k - i;
        if (j >= 1 && j <= 1024) {
            float vu  = D[p1][i - 1];
            float vdg = D[p2][i - 1];
            float vl  = D[p1][i];
            float t1 = vu + A;
            float t2 = vl + A;
            float di = t1 - vdg;
            float inner = (di > 0.f) ? (t1  + log1pf(expf(-di)))
                                     : (vdg + log1pf(expf(di)));
            float dw = inner - t2;
            float outer = (dw > 0.f) ? (inner + log1pf(expf(-dw)))
                                     : (t2    + log1pf(expf(dw)));
            D[cur][i] = Grow[ys[j - 1]] + outer;
            float go1 = expf(inner - outer);
            float wlW = expf(t2 - outer);
            float wuW = go1 * expf(t1 - inner);
            size_t ci = ((size_t)t << 10) + (j - 1);
            wb[ci] = make_float2(wuW, wlW);
            if (FAITHFUL) wdb[ci] = go1 * expf(vdg - inner);
        }
        if (t == 0) D[cur][0] = NEGV;
        if (i == k && k <= 1024) D[cur][k] = NEGV;
        __syncthreads();
    }

    __syncthreads();

    float* ob = out + ((size_t)b << 20);

    for (int k = 2048; k >= 2; --k) {
        const int cur = k % 3, n1 = (k + 1) % 3, n2 = (k + 2) % 3;
        const int j = k - i;
        if (j >= 1 && j <= 1024) {
            float e;
            if (k == 2048) {
                e = 1.0f;
            } else {
                float Eu = E[n1][i + 1];
                float Ed = E[n2][i + 1];
                float El = E[n1][i];
                int iw = (i < 1024) ? i : 1023;
                int jw = (j < 1024) ? j : 1023;
                float2 w_up = wb[((size_t)iw << 10) + (j - 1)];
                float2 w_lf = wb[((size_t)(i - 1) << 10) + jw];
                float w_dd;
                if (FAITHFUL) {
                    w_dd = wdb[((size_t)iw << 10) + jw];
                } else {
                    float2 w_dg = wb[((size_t)iw << 10) + jw];
                    w_dd = 1.0f - w_dg.x - w_dg.y;
                }
                e = Eu * w_up.x + Ed * w_dd + El * w_lf.y;
            }
            E[cur][i] = e;
            ob[((size_t)(j - 1) << 10) + (i - 1)] = e;
        } else {
            E[cur][i] = 0.f;
        }
        __syncthreads();
    }
}

// ---------------------------------------------------------------------------
extern "C" void kernel_launch(void* const* d_in, const int* in_sizes, int n_in,
                              void* d_out, int out_size, void* d_ws, size_t ws_size,
                              hipStream_t stream) {
    const int*   x   = (const int*)d_in[0];
    const int*   y   = (const int*)d_in[1];
    const float* emb = (const float*)d_in[2];
    const float* W   = (const float*)d_in[3];
    const float* b   = (const float*)d_in[4];
    const float* Wg  = (const float*)d_in[5];
    const float* bg  = (const float*)d_in[6];
    float* out = (float*)d_out;

    char* ws = (char*)d_ws;
    double* T    = (double*)(ws + 0);                       // 90112 B
    double* G    = (double*)(ws + 90112);                   // 3872 B
    double* Aarr = (double*)(ws + 94336);                   // 64 B
    float*  bund = (float*)(ws + 131072);                   // 96 MiB (packed diagonals)
    float2* wbuf = (float2*)(ws + 131072);                  // (fallback layout)
    float*  wdbuf = (float*)(ws + 131072 + ((size_t)64 << 20));
    float*  Vbuf = (float*)(ws + 131072 + ((size_t)96 << 20));   // 33.6 MB
    int*    gflag = (int*)(ws + 131072 + ((size_t)96 << 20) + (size_t)8 * 1025 * 1025 * 4);

    k_embed<<<44, 256, 0, stream>>>(emb, W, b, T);
    k_gau<<<1, 512, 0, stream>>>(T, x, y, Wg, bg, G, Aarr);

    const size_t need_old = 131072 + ((size_t)96 << 20);
    const size_t need_new = need_old + (size_t)8 * 1025 * 1025 * 4 + 4096;

    if (ws_size >= need_new) {
        k_vinit<<<8, 1024, 0, stream>>>(Vbuf, gflag);
        k_fwds<<<8 * NB, 256, 0, stream>>>(x, y, G, Aarr, Vbuf, gflag);
        k_wb<<<8 * 1024 * 1024 / 256, 256, 0, stream>>>(Aarr, Vbuf, bund);
        k_bwd16<<<8, 64, 0, stream>>>(bund, out);
    } else if (ws_size >= need_old) {
        k_dp<true><<<8, 1024, 0, stream>>>(x, y, G, Aarr, wbuf, wdbuf, out);
    } else {
        k_dp<false><<<8, 1024, 0, stream>>>(x, y, G, Aarr, wbuf, wdbuf, out);
    }
}

// Round 13
// 3044.233 us; speedup vs baseline: 1.2268x; 1.2268x over previous
//
#include <hip/hip_runtime.h>
#include <cstdint>
#include <cstddef>

#define NEGV -1.0e9f
#define NB 4              // row-blocks per batch
#define BW 4              // waves per row-block

// Branchless logaddexp, bit-identical to the verified branch form.
__device__ __forceinline__ float lse_f(float a, float b) {
    float d = a - b;
    float m = fmaxf(a, b);
    return m + log1pf(expf(-fabsf(d)));
}
__device__ __forceinline__ float cellfwd(float th, float vu, float vdg, float vl, float A) {
    float inner = lse_f(vu + A, vdg);
    float outer = lse_f(inner, vl + A);
    return th + outer;
}

// Packed anti-diagonal geometry for the bundle buffer.
__device__ __forceinline__ void diag_geo(int d, int& st, int& L, int& tlo) {
    if (d < 64)        { st = (d * (d + 1)) >> 1;       L = d + 1;      tlo = 0; }
    else if (d < 1024) { st = 2080 + ((d - 64) << 6);   L = 64;         tlo = 0; }
    else               { int u = d - 1024;
                         st = 63520 + (u << 6) - ((u * (u + 1)) >> 1);
                         L = 63 - u;                    tlo = u + 1; }
}

// ---------------------------------------------------------------------------
// K1: T = emb @ W + b   (f64 accumulate), T: [22][512]
// ---------------------------------------------------------------------------
__global__ void k_embed(const float* __restrict__ emb, const float* __restrict__ W,
                        const float* __restrict__ b, double* __restrict__ T) {
    int idx = blockIdx.x * blockDim.x + threadIdx.x;
    if (idx >= 22 * 512) return;
    int a = idx >> 9, d = idx & 511;
    double acc = (double)b[d];
    const float* er = emb + a * 512;
    for (int k = 0; k < 512; ++k) acc += (double)er[k] * (double)W[k * 512 + d];
    T[idx] = acc;
}

// ---------------------------------------------------------------------------
// K2: G = T @ T^T (22x22), u1/u2 = T @ Wg halves, A[b] via index sums
// ---------------------------------------------------------------------------
__global__ void k_gau(const double* __restrict__ T, const int* __restrict__ x,
                      const int* __restrict__ y, const float* __restrict__ Wg,
                      const float* __restrict__ bg,
                      double* __restrict__ G, double* __restrict__ Aout) {
    __shared__ double u1s[22], u2s[22];
    int t = threadIdx.x;
    if (t < 484) {
        int a = t / 22, c = t % 22;
        const double* ra = T + a * 512;
        const double* rc = T + c * 512;
        double acc = 0.0;
        for (int d = 0; d < 512; ++d) acc += ra[d] * rc[d];
        G[t] = acc;
    }
    if (t < 22) {
        double acc = 0.0;
        const double* ra = T + t * 512;
        for (int d = 0; d < 512; ++d) acc += ra[d] * (double)Wg[d];
        u1s[t] = acc;
    } else if (t >= 64 && t < 86) {
        int a = t - 64;
        double acc = 0.0;
        const double* ra = T + a * 512;
        for (int d = 0; d < 512; ++d) acc += ra[d] * (double)Wg[512 + d];
        u2s[a] = acc;
    }
    __syncthreads();
    int w = t >> 6, lane = t & 63;
    const int* xb = x + w * 1024;
    const int* yb = y + w * 1024;
    double s = 0.0;
    for (int i = lane; i < 1024; i += 64) s += u1s[xb[i]] + u2s[yb[i]];
    for (int off = 32; off > 0; off >>= 1) s += __shfl_down(s, off);
    if (lane == 0) Aout[w] = s * (1.0 / 1024.0) + (double)bg[0];
}

// ---------------------------------------------------------------------------
// K3a: init V boundary (row 0 / col 0) + zero inter-block flags.
// ---------------------------------------------------------------------------
__global__ void k_vinit(float* __restrict__ Vbuf, int* __restrict__ gflag) {
    int b = blockIdx.x, t = threadIdx.x;
    float* Vb = Vbuf + (size_t)b * (1025 * 1025);
    Vb[t] = (t == 0) ? 0.0f : NEGV;                 // V[0][t]
    if (t == 0) Vb[1024] = NEGV;                    // V[0][1024]
    Vb[(size_t)(t + 1) * 1025] = NEGV;              // V[t+1][0]
    if (b == 0 && t < 64) gflag[t] = 0;
}

// ---------------------------------------------------------------------------
// K3b: split banded forward, 2 columns per lane per step. Lane offset stays
//      1 step (no extra pipeline depth); the ~1200cy fixed per-step cost
//      (shfl + guards + selects) amortizes over 2 cells. Cell math verbatim:
//      vA = cellfwd(thA, vuA, sdiag, cB), vB = cellfwd(thB, vuB, vuA, vA).
//      Handoff protocols verbatim r11: intra-block LDS topbuf + 16-col prog
//      (WORKGROUP atomics), inter-block Vbuf + 64-col AGENT gflag (+fence).
// ---------------------------------------------------------------------------
__global__ __launch_bounds__(256) void k_fwds(const int* __restrict__ x,
                                              const int* __restrict__ y,
                                              const double* __restrict__ G,
                                              const double* __restrict__ Aarr,
                                              float* __restrict__ Vbuf,
                                              int* __restrict__ gflag) {
    __shared__ float Gs[484];
    __shared__ int ys_s[1024];
    __shared__ float topbuf[BW][1024];   // topbuf[w][c] = V[256p + 64w][c+1]
    __shared__ int prog[BW];

    const int bid = blockIdx.x;
    const int b = bid & 7;               // batch (XCD-affine)
    const int p = bid >> 3;              // row-block 0..NB-1
    const int tid = threadIdx.x;         // 0..255
    const int w = tid >> 6;              // wave within block
    const int t = tid & 63;              // lane
    const int grow = (p << 8) + tid;     // global (row-1)
    float* Vb = Vbuf + (size_t)b * (1025 * 1025);

    for (int q = tid; q < 484; q += 256) Gs[q] = (float)G[q];
    for (int q = tid; q < 1024; q += 256) ys_s[q] = y[(b << 10) + q];
    if (tid < BW) prog[tid] = 0;
    const int xs = x[(b << 10) + grow];
    __syncthreads();

    const float A = (float)Aarr[b];
    const float* Grow = Gs + xs * 22;
    float* vst = Vb + (size_t)(grow + 1) * 1025 + 1;      // vst[j-1] = V[row][j]
    const float* tsrc = Vb + (size_t)(p << 8) * 1025;     // V[256p][*]

    float cA = NEGV, cB = NEGV;          // carry pair: this lane's (vA, vB)
    // sdiag = V[row-1][jA-1] carry. Seed = V[row-1][0]: 0 only for row 1.
    float sdiag = (p == 0 && w == 0 && t == 0) ? 0.0f : NEGV;
    float chunkv = NEGV;
    int cbase = 0;

    for (int s = 0; s < 512 + 63; ++s) {
        // inter-block chunk (wave 0, p>0): 64 cols every 32 steps
        if (w == 0 && p > 0 && s < 512 && (s & 31) == 0) {
            int tgt = 2 * s + 64; if (tgt > 1024) tgt = 1024;
            while (__hip_atomic_load(&gflag[(b << 2) + p - 1], __ATOMIC_ACQUIRE,
                                     __HIP_MEMORY_SCOPE_AGENT) < tgt)
                __builtin_amdgcn_s_sleep(2);
            chunkv = tsrc[2 * s + 1 + t];    // cols 2s+1 .. 2s+64
            cbase = s;
        }
        // intra-block spin (waves > 0): 16 cols every 8 steps
        if (w > 0 && s < 512 && (s & 7) == 0) {
            int tgt = 2 * s + 16; if (tgt > 1024) tgt = 1024;
            while (__hip_atomic_load(&prog[w], __ATOMIC_ACQUIRE,
                                     __HIP_MEMORY_SCOPE_WORKGROUP) < tgt)
                __builtin_amdgcn_s_sleep(1);
        }
        const float shA = __shfl_up(cA, 1);          // lane t-1: v(r-1, jA)
        const float shB = __shfl_up(cB, 1);          // lane t-1: v(r-1, jB)
        const int cidx = (2 * (s - cbase)) & 62;     // chunk lane index (wave 0)
        const float ckA = __shfl(chunkv, cidx);
        const float ckB = __shfl(chunkv, cidx + 1);
        const int q = s - t;
        if (q >= 0 && q < 512) {
            const int jA = 2 * q + 1, jB = jA + 1;
            float vuA, vuB;
            if (t == 0) {
                if (w == 0) {
                    if (p == 0) { vuA = NEGV; vuB = NEGV; }   // row 0 boundary
                    else        { vuA = ckA;  vuB = ckB;  }
                } else {
                    vuA = topbuf[w][jA - 1];
                    vuB = topbuf[w][jB - 1];
                }
            } else { vuA = shA; vuB = shB; }
            const float thA = Grow[ys_s[jA - 1]];
            const float thB = Grow[ys_s[jB - 1]];
            float vA = cellfwd(thA, vuA, sdiag, cB, A);   // cell (r, jA)
            float vB = cellfwd(thB, vuB, vuA, vA, A);     // cell (r, jB)
            vst[jA - 1] = vA;                             // stores stay in flight
            vst[jB - 1] = vB;
            if (t == 63) {
                if (w < BW - 1) {
                    topbuf[w + 1][jA - 1] = vA;
                    topbuf[w + 1][jB - 1] = vB;
                    if ((jB & 15) == 0)
                        __hip_atomic_store(&prog[w + 1], jB, __ATOMIC_RELEASE,
                                           __HIP_MEMORY_SCOPE_WORKGROUP);
                } else if (p < NB - 1) {
                    if ((jB & 63) == 0) {
                        __threadfence();
                        __hip_atomic_store(&gflag[(b << 2) + p], jB,
                                           __ATOMIC_RELEASE, __HIP_MEMORY_SCOPE_AGENT);
                    }
                }
            }
            sdiag = vuB;                 // V[r-1][jB] = next pair's vdg source
            cA = vA; cB = vB;
        }
    }
}

// ---------------------------------------------------------------------------
// K4: weight kernel — recompute each cell's softmax weights (bit-identical
//     inputs from stored V), scatter into the packed-diagonal bundle layout.
// ---------------------------------------------------------------------------
__global__ __launch_bounds__(256) void k_wb(const double* __restrict__ Aarr,
                                            const float* __restrict__ Vbuf,
                                            float* __restrict__ bw) {
    int idx = blockIdx.x * 256 + threadIdx.x;
    int b = idx >> 20;
    int cell = idx & 1048575;
    int i = (cell >> 10) + 1;        // 1..1024
    int j = (cell & 1023) + 1;       // 1..1024
    const float* Vb = Vbuf + (size_t)b * (1025 * 1025);
    float vu  = Vb[(size_t)(i - 1) * 1025 + j];
    float vdg = Vb[(size_t)(i - 1) * 1025 + (j - 1)];
    float vl  = Vb[(size_t)i * 1025 + (j - 1)];
    float A = (float)Aarr[b];
    float t1 = vu + A;
    float t2 = vl + A;
    float di = t1 - vdg;
    float inner = (di > 0.f) ? (t1  + log1pf(expf(-di)))
                             : (vdg + log1pf(expf(di)));
    float dw = inner - t2;
    float outer = (dw > 0.f) ? (inner + log1pf(expf(-dw)))
                             : (t2    + log1pf(expf(dw)));
    float go1 = expf(inner - outer);
    float wlW = expf(t2 - outer);
    float wuW = go1 * expf(t1 - inner);
    float wdW = go1 * expf(vdg - inner);
    float* bbp = bw + (size_t)b * 3145728;

    if (i >= 2) {        // wu -> consumer (i-1, j)
        int rb = (i - 2) >> 4, q = (i - 2) & 15, cj = j - 1;
        int st, L, tlo; diag_geo(rb + cj, st, L, tlo);
        int f = 3 * q;
        bbp[(size_t)st * 48 + (size_t)(f >> 2) * 4 * L + ((rb - tlo) << 2) + (f & 3)] = wuW;
    }
    if (i >= 2 && j >= 2) {   // wd -> consumer (i-1, j-1)
        int rb = (i - 2) >> 4, q = (i - 2) & 15, cj = j - 2;
        int st, L, tlo; diag_geo(rb + cj, st, L, tlo);
        int f = 3 * q + 1;
        bbp[(size_t)st * 48 + (size_t)(f >> 2) * 4 * L + ((rb - tlo) << 2) + (f & 3)] = wdW;
    }
    if (j >= 2) {        // wl -> consumer (i, j-1)
        int rb = (i - 1) >> 4, q = (i - 1) & 15, cj = j - 2;
        int st, L, tlo; diag_geo(rb + cj, st, L, tlo);
        int f = 3 * q + 2;
        bbp[(size_t)st * 48 + (size_t)(f >> 2) * 4 * L + ((rb - tlo) << 2) + (f & 3)] = wlW;
    }
}

// ---------------------------------------------------------------------------
// K5: single-launch backward, packed-diagonal coalesced bundle reads.
//     (verbatim from the verified round-9 kernel; bit-identical E order)
// ---------------------------------------------------------------------------
__global__ __launch_bounds__(64) void k_bwd16(const float* __restrict__ bw,
                                              float* __restrict__ out) {
    const int t = threadIdx.x;
    const int b = blockIdx.x;
    const float* bb = bw + (size_t)b * 3145728;
    float* ob = out + ((size_t)b << 20);
    const int r0 = t << 4;              // (i-1) base = 16t

    float e[16];
    float4 cwv[12], pfv[12];
    #pragma unroll
    for (int q = 0; q < 16; ++q) e[q] = 0.f;

    {
        int st, L, tlo; diag_geo(t + 1023, st, L, tlo);
        const float* base = bb + (size_t)st * 48;
        #pragma unroll
        for (int k = 0; k < 12; ++k)
            cwv[k] = *(const float4*)(base + (size_t)k * 4 * L);
    }

    float sdb = 0.f;
    for (int s = 0; s < 1087; ++s) {
        float dn = __shfl_down(e[0], 1);    // lane t+1's top value at col cj
        const int d = 1086 - s;
        const int cj = d - t;               // this lane's column (j-1)
        if (cj >= 0 && cj < 1024) {
            {
                int st, L, tlo; diag_geo(d - 1, st, L, tlo);
                const int p = t - tlo;
                const float* base = bb + (size_t)st * 48 + ((size_t)p << 2);
                #pragma unroll
                for (int k = 0; k < 12; ++k)
                    pfv[k] = *(const float4*)(base + (size_t)k * 4 * L);
            }
            const float* F = (const float*)cwv;

            float old_b = e[15];
            float eu = (t == 63) ? 0.f : dn;
            float ed = (t == 63) ? 0.f : sdb;
            float v = eu * F[45] + ed * F[46] + old_b * F[47];
            if (t == 63 && cj == 1023) v = 1.0f;    // seed E[1024][1024] = 1
            e[15] = v;
            float new_b = v;
            #pragma unroll
            for (int q = 14; q >= 0; --q) {
                float oq = e[q];
                v = new_b * F[3 * q] + old_b * F[3 * q + 1] + oq * F[3 * q + 2];
                e[q] = v;
                new_b = v; old_b = oq;
            }
            #pragma unroll
            for (int k = 0; k < 4; ++k)
                *(float4*)&ob[(size_t)cj * 1024 + r0 + 4 * k] =
                    make_float4(e[4*k], e[4*k+1], e[4*k+2], e[4*k+3]);
            #pragma unroll
            for (int k = 0; k < 12; ++k) cwv[k] = pfv[k];
        }
        sdb = dn;
    }
}

// ---------------------------------------------------------------------------
// Fallback: round-2 monolithic forward+backward (used only if ws too small).
// ---------------------------------------------------------------------------
template <bool FAITHFUL>
__global__ __launch_bounds__(1024) void k_dp(const int* __restrict__ x,
                                             const int* __restrict__ y,
                                             const double* __restrict__ G,
                                             const double* __restrict__ Aarr,
                                             float2* __restrict__ wbuf,
                                             float* __restrict__ wdbuf,
                                             float* __restrict__ out) {
    __shared__ float Gs[484];
    __shared__ int xs[1024], ys[1024];
    __shared__ float D[3][1025];
    __shared__ float E[3][1026];

    const int b = blockIdx.x;
    const int t = threadIdx.x;
    const int i = t + 1;

    if (t < 484) Gs[t] = (float)G[t];
    xs[t] = x[(b << 10) + t];
    ys[t] = y[(b << 10) + t];
    D[0][t + 1] = NEGV;
    D[1][t + 1] = NEGV;
    E[0][t] = 0.f; E[1][t] = 0.f; E[2][t] = 0.f;
    if (t == 0) {
        D[0][0] = 0.0f;
        D[1][0] = NEGV;
        E[0][1024] = 0.f; E[0][1025] = 0.f;
        E[1][1024] = 0.f; E[1][1025] = 0.f;
        E[2][1024] = 0.f; E[2][1025] = 0.f;
    }
    __syncthreads();

    const float A = (float)Aarr[b];
    const float* Grow = Gs + xs[t] * 22;
    float2* wb = wbuf + ((size_t)b << 20);
    float*  wdb = wdbuf + ((size_t)b << 20);

    for (int k = 2; k <= 2048; ++k) {
        const int cur = k % 3, p1 = (k + 2) % 3, p2 = (k + 1) % 3;
        const int j = k - i;
        if (j >= 1 && j <= 1024) {
            float vu  = D[p1][i - 1];
            float vdg = D[p2][i - 1];
            float vl  = D[p1][i];
            float t1 = vu + A;
            float t2 = vl + A;
            float di = t1 - vdg;
            float inner = (di > 0.f) ? (t1  + log1pf(expf(-di)))
                                     : (vdg + log1pf(expf(di)));
            float dw = inner - t2;
            float outer = (dw > 0.f) ? (inner + log1pf(expf(-dw)))
                                     : (t2    + log1pf(expf(dw)));
            D[cur][i] = Grow[ys[j - 1]] + outer;
            float go1 = expf(inner - outer);
            float wlW = expf(t2 - outer);
            float wuW = go1 * expf(t1 - inner);
            size_t ci = ((size_t)t << 10) + (j - 1);
            wb[ci] = make_float2(wuW, wlW);
            if (FAITHFUL) wdb[ci] = go1 * expf(vdg - inner);
        }
        if (t == 0) D[cur][0] = NEGV;
        if (i == k && k <= 1024) D[cur][k] = NEGV;
        __syncthreads();
    }

    __syncthreads();

    float* ob = out + ((size_t)b << 20);

    for (int k = 2048; k >= 2; --k) {
        const int cur = k % 3, n1 = (k + 1) % 3, n2 = (k + 2) % 3;
        const int j = k - i;
        if (j >= 1 && j <= 1024) {
            float e;
            if (k == 2048) {
                e = 1.0f;
            } else {
                float Eu = E[n1][i + 1];
                float Ed = E[n2][i + 1];
                float El = E[n1][i];
                int iw = (i < 1024) ? i : 1023;
                int jw = (j < 1024) ? j : 1023;
                float2 w_up = wb[((size_t)iw << 10) + (j - 1)];
                float2 w_lf = wb[((size_t)(i - 1) << 10) + jw];
                float w_dd;
                if (FAITHFUL) {
                    w_dd = wdb[((size_t)iw << 10) + jw];
                } else {
                    float2 w_dg = wb[((size_t)iw << 10) + jw];
                    w_dd = 1.0f - w_dg.x - w_dg.y;
                }
                e = Eu * w_up.x + Ed * w_dd + El * w_lf.y;
            }
            E[cur][i] = e;
            ob[((size_t)(j - 1) << 10) + (i - 1)] = e;
        } else {
            E[cur][i] = 0.f;
        }
        __syncthreads();
    }
}

// ---------------------------------------------------------------------------
extern "C" void kernel_launch(void* const* d_in, const int* in_sizes, int n_in,
                              void* d_out, int out_size, void* d_ws, size_t ws_size,
                              hipStream_t stream) {
    const int*   x   = (const int*)d_in[0];
    const int*   y   = (const int*)d_in[1];
    const float* emb = (const float*)d_in[2];
    const float* W   = (const float*)d_in[3];
    const float* b   = (const float*)d_in[4];
    const float* Wg  = (const float*)d_in[5];
    const float* bg  = (const float*)d_in[6];
    float* out = (float*)d_out;

    char* ws = (char*)d_ws;
    double* T    = (double*)(ws + 0);                       // 90112 B
    double* G    = (double*)(ws + 90112);                   // 3872 B
    double* Aarr = (double*)(ws + 94336);                   // 64 B
    float*  bund = (float*)(ws + 131072);                   // 96 MiB (packed diagonals)
    float2* wbuf = (float2*)(ws + 131072);                  // (fallback layout)
    float*  wdbuf = (float*)(ws + 131072 + ((size_t)64 << 20));
    float*  Vbuf = (float*)(ws + 131072 + ((size_t)96 << 20));   // 33.6 MB
    int*    gflag = (int*)(ws + 131072 + ((size_t)96 << 20) + (size_t)8 * 1025 * 1025 * 4);

    k_embed<<<44, 256, 0, stream>>>(emb, W, b, T);
    k_gau<<<1, 512, 0, stream>>>(T, x, y, Wg, bg, G, Aarr);

    const size_t need_old = 131072 + ((size_t)96 << 20);
    const size_t need_new = need_old + (size_t)8 * 1025 * 1025 * 4 + 4096;

    if (ws_size >= need_new) {
        k_vinit<<<8, 1024, 0, stream>>>(Vbuf, gflag);
        k_fwds<<<8 * NB, 256, 0, stream>>>(x, y, G, Aarr, Vbuf, gflag);
        k_wb<<<8 * 1024 * 1024 / 256, 256, 0, stream>>>(Aarr, Vbuf, bund);
        k_bwd16<<<8, 64, 0, stream>>>(bund, out);
    } else if (ws_size >= need_old) {
        k_dp<true><<<8, 1024, 0, stream>>>(x, y, G, Aarr, wbuf, wdbuf, out);
    } else {
        k_dp<false><<<8, 1024, 0, stream>>>(x, y, G, Aarr, wbuf, wdbuf, out);
    }
}